// Round 5
// baseline (388.712 us; speedup 1.0000x reference)
//
#include <hip/hip_runtime.h>
#include <math.h>

#define BATCH 256
#define QL 50
#define EMB 50
#define DL 2000
#define NB 11
#define SEG 8
#define RPS 250      // d rows per segment (DL/SEG), 1 row per thread
#define TPB 256
#define EP 25        // e-pairs per d row
#define QCH 10       // q per chunk
#define NCH 5        // q chunks
#define NEC 5        // e chunks (5 float2 each)
#define QPAD 12      // padded floats per (qc,ec,j) q-slice (16B-aligned rows)
#define HB (QL * NB) // 550

#define FOR_J10(M) M(0) M(1) M(2) M(3) M(4) M(5) M(6) M(7) M(8) M(9)
#define DCLA(j) float a##j = 0.f;

// inner: 10 q floats from wave-uniform address (-> scalar loads), 10 fmacs.
// e ascending e = ec*10 + 0..9 — bitwise-identical chain to the R4 kernel.
#define FMAQ(j) { \
  const float* qrow = qpc + (j) * QPAD; \
  const float4 qa  = *(const float4*)(qrow); \
  const float4 qb4 = *(const float4*)(qrow + 4); \
  const float2 qc2 = *(const float2*)(qrow + 8); \
  a##j = fmaf(dv0.x, qa.x,  a##j); a##j = fmaf(dv0.y, qa.y,  a##j); \
  a##j = fmaf(dv1.x, qa.z,  a##j); a##j = fmaf(dv1.y, qa.w,  a##j); \
  a##j = fmaf(dv2.x, qb4.x, a##j); a##j = fmaf(dv2.y, qb4.y, a##j); \
  a##j = fmaf(dv3.x, qb4.z, a##j); a##j = fmaf(dv3.y, qb4.w, a##j); \
  a##j = fmaf(dv4.x, qc2.x, a##j); a##j = fmaf(dv4.y, qc2.y, a##j); }

// binning + ballot histogram — verbatim arithmetic from the passing kernels
#define HIST1(j) { const int q = qc * QCH + (j); \
  if (s_qv[q]) { \
    const float s_  = a##j * s_qrn[q] * drn; \
    const float tt_ = ((s_ + 1.000001f) * 0.5f) * 10.0f; \
    int bb_ = (int)tt_; bb_ = bb_ < 0 ? 0 : (bb_ > 10 ? 10 : bb_); \
    const int bin_ = dval ? bb_ : -1; \
    unsigned cnt_ = 0; \
    _Pragma("unroll") \
    for (int k = 0; k < NB; ++k) { \
      const unsigned long long m_ = __ballot(bin_ == k); \
      if (lane == k) cnt_ = (unsigned)__popcll(m_); \
    } \
    if (lane < NB && cnt_) atomicAdd(&s_hist[q * NB + lane], cnt_); \
  } }

// ---------------- gate kernel: zero hist + gate dot + q repack ----------------
__global__ __launch_bounds__(TPB)
void gate_kernel(const float* __restrict__ qe,
                 const float* __restrict__ Wg,
                 float* __restrict__ gate,
                 float* __restrict__ qpad,     // [B][NCH][NEC][QCH][QPAD]
                 unsigned* __restrict__ g_hist)
{
    const int b = blockIdx.x;
    const int t = threadIdx.x;
    const float* qb = qe + (size_t)b * QL * EMB;

    for (int i = t; i < HB; i += TPB) g_hist[(size_t)b * HB + i] = 0u;

    // repack: qpad[(b*250 + i)*12 + k] = qe[b][qc*10+j][ec*10+k], i=((qc*5)+ec)*10+j
    for (int i = t; i < NCH * NEC * QCH; i += TPB) {
        const int qc  = i / (NEC * QCH);
        const int rem = i - qc * (NEC * QCH);
        const int ec  = rem / QCH;
        const int j   = rem - ec * QCH;
        const int q   = qc * QCH + j;
        float* dst = qpad + ((size_t)b * (NCH * NEC * QCH) + i) * QPAD;
        const float* srcq = qb + q * EMB + ec * 10;
        #pragma unroll
        for (int k = 0; k < 10; ++k) dst[k] = srcq[k];
        dst[10] = 0.f; dst[11] = 0.f;
    }

    // gate dot: exact replica of the verified reduction (passed, absmax 0.0)
    float a2 = 0.f;
    for (int i = t; i < QL * EMB; i += TPB)
        a2 = fmaf(qb[i], Wg[i], a2);
    #pragma unroll
    for (int off = 32; off > 0; off >>= 1) a2 += __shfl_down(a2, off, 64);
    __shared__ float r2s[4];
    if ((t & 63) == 0) r2s[t >> 6] = a2;
    __syncthreads();
    if (t == 0) gate[b] = r2s[0] + r2s[1] + r2s[2] + r2s[3];
}

// ---------------- main kernel: d in LDS, q via wave-uniform scalar loads ----------------
__global__ __launch_bounds__(TPB, 3)
void sim_hist_kernel(const float* __restrict__ de,
                     const int*   __restrict__ did,
                     const float* __restrict__ qe,
                     const float* __restrict__ qpad,
                     const int*   __restrict__ qid,
                     unsigned*    __restrict__ g_hist)
{
    const int bid  = blockIdx.x;
    const int b    = bid >> 3;
    const int seg  = bid & 7;
    const int t    = threadIdx.x;
    const int lane = t & 63;

    __shared__ float2   d2[EP][TPB];    // 51,200 B (lane-minor: 2-way bank, free)
    __shared__ float    s_qrn[QL];
    __shared__ int      s_qv[QL];
    __shared__ unsigned s_hist[HB];     // total 53,800 B -> 54,272 -> 3 blocks/CU

    for (int i = t; i < HB; i += TPB) s_hist[i] = 0u;

    const float* qbase = qe + (size_t)b * QL * EMB;
    if (t < QL) {   // q-norms + validity (round-0 verbatim)
        const float* qr = qbase + t * EMB;
        float ss = 0.f;
        #pragma unroll
        for (int e = 0; e < EMB; ++e) ss = fmaf(qr[e], qr[e], ss);
        s_qrn[t] = 1.0f / (sqrtf(ss) + 1e-8f);
        s_qv[t]  = (qid[(size_t)b * QL + t] > 0) ? 1 : 0;
    }

    // ---- stage this thread's d row into LDS; norm chain e-ascending (verbatim) ----
    const bool ok  = t < RPS;
    const int  row = seg * RPS + (ok ? t : 0);
    const float* src = de + ((size_t)b * DL + row) * EMB;
    float ss = 0.f;
    #pragma unroll
    for (int ep = 0; ep < EP; ++ep) {
        const float2 v = *(const float2*)(src + 2 * ep);
        ss = fmaf(v.x, v.x, ss);
        ss = fmaf(v.y, v.y, ss);
        d2[ep][t] = v;
    }
    const float drn  = 1.0f / (sqrtf(ss) + 1e-8f);
    const int   dval = (ok && did[(size_t)b * DL + row] > 0) ? 1 : 0;

    __syncthreads();

    const float* qpb = qpad + (size_t)b * (NCH * NEC * QCH) * QPAD;

    #pragma unroll 1
    for (int qc = 0; qc < NCH; ++qc) {
        FOR_J10(DCLA)                       // a0..a9 = 0
        #pragma unroll 1
        for (int ec = 0; ec < NEC; ++ec) {  // ROLLED: bounds live set (proven R4)
            const float2 dv0 = d2[ec * 5 + 0][t];
            const float2 dv1 = d2[ec * 5 + 1][t];
            const float2 dv2 = d2[ec * 5 + 2][t];
            const float2 dv3 = d2[ec * 5 + 3][t];
            const float2 dv4 = d2[ec * 5 + 4][t];
            const float* qpc = qpb + ((qc * NEC + ec) * QCH) * QPAD; // uniform
            FOR_J10(FMAQ)                   // 100 fmac, q via scalar pipe
        }
        FOR_J10(HIST1)                      // bin + ballot for this q chunk
    }

    __syncthreads();
    for (int i = t; i < HB; i += TPB) {
        const unsigned cv = s_hist[i];
        if (cv) atomicAdd(&g_hist[(size_t)b * HB + i], cv);
    }
}

// ---------------- ffn dot per batch (verbatim, passed) ----------------
__global__ __launch_bounds__(TPB)
void ffn_kernel(const unsigned* __restrict__ g_hist,
                const float* __restrict__ W1,
                const float* __restrict__ bias,
                float* __restrict__ ffn)
{
    const int b = blockIdx.x;
    const int t = threadIdx.x;

    float a1 = 0.f;
    for (int i = t; i < HB; i += TPB)
        a1 = fmaf(logf((float)g_hist[(size_t)b * HB + i] + 1e-5f), W1[i], a1);

    #pragma unroll
    for (int off = 32; off > 0; off >>= 1) a1 += __shfl_down(a1, off, 64);
    __shared__ float r1s[4];
    if ((t & 63) == 0) r1s[t >> 6] = a1;
    __syncthreads();
    if (t == 0) ffn[b] = r1s[0] + r1s[1] + r1s[2] + r1s[3] + bias[0];
}

// ---------------- softmax over batch + final score (verbatim, passed) ----------------
__global__ __launch_bounds__(TPB)
void score_kernel(const float* __restrict__ ffn,
                  const float* __restrict__ gate,
                  float* __restrict__ out)
{
    const int t = threadIdx.x;  // one block of 256 == BATCH
    __shared__ float buf[4];
    __shared__ float sM, sZ, sS;

    const float g = gate[t];

    float m = g;
    #pragma unroll
    for (int off = 32; off > 0; off >>= 1) m = fmaxf(m, __shfl_down(m, off, 64));
    if ((t & 63) == 0) buf[t >> 6] = m;
    __syncthreads();
    if (t == 0) sM = fmaxf(fmaxf(buf[0], buf[1]), fmaxf(buf[2], buf[3]));
    __syncthreads();

    const float e = expf(g - sM);
    float z = e;
    #pragma unroll
    for (int off = 32; off > 0; off >>= 1) z += __shfl_down(z, off, 64);
    __syncthreads();
    if ((t & 63) == 0) buf[t >> 6] = z;
    __syncthreads();
    if (t == 0) sZ = buf[0] + buf[1] + buf[2] + buf[3];
    __syncthreads();

    float p = e / sZ;
    float s = p;
    #pragma unroll
    for (int off = 32; off > 0; off >>= 1) s += __shfl_down(s, off, 64);
    __syncthreads();
    if ((t & 63) == 0) buf[t >> 6] = s;
    __syncthreads();
    if (t == 0) sS = buf[0] + buf[1] + buf[2] + buf[3];
    __syncthreads();

    out[t] = ffn[t] * sS;
}

// ---------------- launcher ----------------
extern "C" void kernel_launch(void* const* d_in, const int* in_sizes, int n_in,
                              void* d_out, int out_size, void* d_ws, size_t ws_size,
                              hipStream_t stream)
{
    const float* qe  = (const float*)d_in[0];
    const float* de  = (const float*)d_in[1];
    const float* W1  = (const float*)d_in[2];
    const float* b1  = (const float*)d_in[3];
    const float* Wg  = (const float*)d_in[4];
    const int*   qid = (const int*)d_in[5];
    const int*   did = (const int*)d_in[6];
    float* out = (float*)d_out;

    // workspace layout (~3.64 MB)
    char* ws = (char*)d_ws;
    float*    qpad   = (float*)ws;                    // 3,072,000 B
    unsigned* g_hist = (unsigned*)(ws + 3072000);     //   563,200 B
    float*    ffn    = (float*)(ws + 3072000 + 563200); //   1,024 B
    float*    gate   = ffn + BATCH;                   //     1,024 B

    gate_kernel<<<BATCH, TPB, 0, stream>>>(qe, Wg, gate, qpad, g_hist);
    sim_hist_kernel<<<BATCH * SEG, TPB, 0, stream>>>(de, did, qe, qpad, qid, g_hist);
    ffn_kernel<<<BATCH, TPB, 0, stream>>>(g_hist, W1, b1, ffn);
    score_kernel<<<1, TPB, 0, stream>>>(ffn, gate, out);
}